// Round 3
// baseline (5738.364 us; speedup 1.0000x reference)
//
#include <hip/hip_runtime.h>
#include <hip/hip_bf16.h>
#include <math.h>

#define C_   1024
#define P_   2304      // 48*48
#define S4   331776    // 24^4

typedef __attribute__((ext_vector_type(8))) short short8;
typedef __attribute__((ext_vector_type(4))) float f32x4;

__device__ inline unsigned short f2bf(float v) {
  unsigned u = __builtin_bit_cast(unsigned, v);
  u += 0x7fffu + ((u >> 16) & 1u);          // RNE
  return (unsigned short)(u >> 16);
}
__device__ inline float bf2f(unsigned short h) {
  unsigned u = ((unsigned)h) << 16;
  return __builtin_bit_cast(float, u);
}

// ---------------- K1: transpose + bf16 hi/lo split + sumsq partials --------
__global__ __launch_bounds__(256) void k_prep(
    const float* __restrict__ fA, const float* __restrict__ fB, int b,
    unsigned short* __restrict__ TAhi, unsigned short* __restrict__ TAlo,
    unsigned short* __restrict__ TBhi, unsigned short* __restrict__ TBlo,
    float* __restrict__ part) {
  __shared__ float ld[64 * 65];
  __shared__ float pslds[512];
  const int c0 = blockIdx.x * 64, p0 = blockIdx.y * 64, f = blockIdx.z;
  const float* src = (f ? fB : fA) + (size_t)b * C_ * P_;
  unsigned short* Thi = f ? TBhi : TAhi;
  unsigned short* Tlo = f ? TBlo : TAlo;
  const int t = threadIdx.x;
#pragma unroll
  for (int e = 0; e < 4; ++e) {
    int cid = t + e * 256;                  // 0..1023
    int r = cid >> 4, ch = cid & 15;
    float4 v = *(const float4*)&src[(size_t)(c0 + r) * P_ + p0 + ch * 4];
    ld[r * 65 + ch * 4 + 0] = v.x;
    ld[r * 65 + ch * 4 + 1] = v.y;
    ld[r * 65 + ch * 4 + 2] = v.z;
    ld[r * 65 + ch * 4 + 3] = v.w;
  }
  __syncthreads();
#pragma unroll
  for (int e = 0; e < 2; ++e) {
    int ocid = t + e * 256;                 // 0..511
    int pl = ocid >> 3, c8 = ocid & 7;
    unsigned short hi[8], lo[8];
    float sq = 0.f;
#pragma unroll
    for (int s = 0; s < 8; ++s) {
      float v = ld[(c8 * 8 + s) * 65 + pl];
      unsigned short h = f2bf(v);
      float rem = v - bf2f(h);
      hi[s] = h; lo[s] = f2bf(rem);
      sq = fmaf(v, v, sq);
    }
    size_t go = (size_t)(p0 + pl) * C_ + c0 + c8 * 8;
    *(uint4*)&Thi[go] = *(uint4*)hi;
    *(uint4*)&Tlo[go] = *(uint4*)lo;
    pslds[ocid] = sq;
  }
  __syncthreads();
  if (t < 64) {
    float s = 0.f;
#pragma unroll
    for (int c8 = 0; c8 < 8; ++c8) s += pslds[t * 8 + c8];
    part[(size_t)(f * 16 + blockIdx.x) * P_ + p0 + t] = s;
  }
}

// ---------------- K2: finalize inverse norms (per batch) -------------------
__global__ void k_invnorm(const float* __restrict__ part, float* __restrict__ inv, int b) {
  int p = blockIdx.x * 256 + threadIdx.x;
  int f = blockIdx.y;
  float s = 1e-6f;
  for (int ct = 0; ct < 16; ++ct) s += part[(size_t)(f * 16 + ct) * P_ + p];
  inv[(size_t)(f * 8 + b) * P_ + p] = 1.0f / sqrtf(s);
}

// ---------------- K3: bf16x3 MFMA correlation + relu/norm/4D-maxpool -------
__global__ __launch_bounds__(256) void k_corr_mfma(
    const unsigned short* __restrict__ TAhi, const unsigned short* __restrict__ TAlo,
    const unsigned short* __restrict__ TBhi, const unsigned short* __restrict__ TBlo,
    const float* __restrict__ invn, int b, float* __restrict__ out) {
  __shared__ __align__(16) char lds_raw[37248];
  unsigned short* stage = (unsigned short*)lds_raw;   // 4 arrays of 96x40
  float* epi = (float*)lds_raw;                       // 96x97 f32 overlay

  const int ti = blockIdx.x / 24, tj = blockIdx.x % 24;
  const int p0 = ti * 96, q0 = tj * 96;
  const int t = threadIdx.x;
  const int lane = t & 63, w = t >> 6;
  const int wr = w >> 1, wc = w & 1;
  const int m15 = lane & 15, q4 = lane >> 4;
  const int koff = q4 * 8;

  f32x4 acc[3][3];
#pragma unroll
  for (int a = 0; a < 3; ++a)
#pragma unroll
    for (int c = 0; c < 3; ++c) acc[a][c] = (f32x4){0.f, 0.f, 0.f, 0.f};

  uint4 pre[6];
  const unsigned short* gsrc[6];
  int ldsoff[6];
#pragma unroll
  for (int e = 0; e < 6; ++e) {
    int cid = t + e * 256;                 // 0..1535
    int arr = cid / 384, wi = cid % 384;
    int rr = wi >> 2, kc = wi & 3;
    const unsigned short* base = (arr == 0) ? TAhi : (arr == 1) ? TAlo
                               : (arr == 2) ? TBhi : TBlo;
    int pb = (arr < 2) ? p0 : q0;
    gsrc[e] = base + (size_t)(pb + rr) * C_ + kc * 8;
    ldsoff[e] = arr * 3840 + rr * 40 + kc * 8;
  }
#pragma unroll
  for (int e = 0; e < 6; ++e) pre[e] = *(const uint4*)(gsrc[e]);   // kt=0

  for (int kt = 0; kt < C_; kt += 32) {
    __syncthreads();
#pragma unroll
    for (int e = 0; e < 6; ++e) *(uint4*)&stage[ldsoff[e]] = pre[e];
    __syncthreads();
    if (kt + 32 < C_) {
#pragma unroll
      for (int e = 0; e < 6; ++e) pre[e] = *(const uint4*)(gsrc[e] + kt + 32);
    }
    const unsigned short* Ah = stage;
    const unsigned short* Al = stage + 3840;
    const unsigned short* Bh = stage + 7680;
    const unsigned short* Bl = stage + 11520;
    short8 ah[3], al[3], bh[3], bl[3];
#pragma unroll
    for (int a = 0; a < 3; ++a) {
      int row = wr * 48 + a * 16 + m15;
      ah[a] = *(const short8*)&Ah[row * 40 + koff];
      al[a] = *(const short8*)&Al[row * 40 + koff];
    }
#pragma unroll
    for (int c = 0; c < 3; ++c) {
      int row = wc * 48 + c * 16 + m15;
      bh[c] = *(const short8*)&Bh[row * 40 + koff];
      bl[c] = *(const short8*)&Bl[row * 40 + koff];
    }
#pragma unroll
    for (int a = 0; a < 3; ++a)
#pragma unroll
      for (int c = 0; c < 3; ++c)
        acc[a][c] = __builtin_amdgcn_mfma_f32_16x16x32_bf16(ah[a], bh[c], acc[a][c], 0, 0, 0);
#pragma unroll
    for (int a = 0; a < 3; ++a)
#pragma unroll
      for (int c = 0; c < 3; ++c)
        acc[a][c] = __builtin_amdgcn_mfma_f32_16x16x32_bf16(ah[a], bl[c], acc[a][c], 0, 0, 0);
#pragma unroll
    for (int a = 0; a < 3; ++a)
#pragma unroll
      for (int c = 0; c < 3; ++c)
        acc[a][c] = __builtin_amdgcn_mfma_f32_16x16x32_bf16(al[a], bh[c], acc[a][c], 0, 0, 0);
  }
  __syncthreads();

  const float* invA = invn + (size_t)b * P_;
  const float* invB = invn + (size_t)(8 + b) * P_;
  float ib[3];
#pragma unroll
  for (int c = 0; c < 3; ++c) ib[c] = invB[q0 + wc * 48 + c * 16 + m15];
#pragma unroll
  for (int a = 0; a < 3; ++a) {
#pragma unroll
    for (int reg = 0; reg < 4; ++reg) {
      int pl = wr * 48 + a * 16 + q4 * 4 + reg;
      float ia = invA[p0 + pl];
#pragma unroll
      for (int c = 0; c < 3; ++c) {
        int ql = wc * 48 + c * 16 + m15;
        epi[pl * 97 + ql] = acc[a][c][reg] * ia * ib[c];
      }
    }
  }
  __syncthreads();

  for (int idx = t; idx < 576; idx += 256) {
    int j = idx / 24, l = idx % 24;
    float m = -1e30f;
#pragma unroll
    for (int dh = 0; dh < 2; ++dh)
#pragma unroll
      for (int dw = 0; dw < 2; ++dw) {
        int row = dh * 48 + 2 * j + dw;
#pragma unroll
        for (int d2 = 0; d2 < 2; ++d2)
#pragma unroll
          for (int dw2 = 0; dw2 < 2; ++dw2)
            m = fmaxf(m, epi[row * 97 + d2 * 48 + 2 * l + dw2]);
      }
    float r = fmaxf(m, 0.f);
    float v = r / sqrtf(r * r + 1e-6f);
    out[(size_t)(ti * 24 + j) * 576 + tj * 24 + l] = v;
  }
}

// ---------------- K4a: row max (over kl, per ij) ---------------------------
__global__ void k_rowmax(const float* __restrict__ x, float* __restrict__ amax) {
  int row = blockIdx.x;                       // b*576 + ij
  const float* r = x + (size_t)row * 576;
  float m = -1e30f;
  for (int e = threadIdx.x; e < 576; e += 64) m = fmaxf(m, r[e]);
  for (int off = 32; off > 0; off >>= 1) m = fmaxf(m, __shfl_down(m, off, 64));
  if (threadIdx.x == 0) amax[row] = m;
}

// ---------------- K4b: col max (over ij, per kl) ---------------------------
__global__ void k_colmax(const float* __restrict__ x, float* __restrict__ bmax) {
  __shared__ float pl[4][64];
  int b = blockIdx.x, klc = blockIdx.y * 64;
  int t = threadIdx.x;
  int kl = klc + (t & 63), seg = t >> 6;
  const float* xb = x + (size_t)b * S4;
  float m = -1e30f;
  for (int ij = seg * 144; ij < (seg + 1) * 144; ++ij)
    m = fmaxf(m, xb[(size_t)ij * 576 + kl]);
  pl[seg][t & 63] = m;
  __syncthreads();
  if (t < 64) {
    float r = fmaxf(fmaxf(pl[0][t], pl[1][t]), fmaxf(pl[2][t], pl[3][t]));
    bmax[b * 576 + klc + t] = r;
  }
}

// ---------------- K5: mutual matching elementwise --------------------------
__global__ void k_mm_apply(const float* __restrict__ x,
                           const float* __restrict__ amax,
                           const float* __restrict__ bmax,
                           float* __restrict__ y) {
  int i = blockIdx.x * 256 + threadIdx.x;     // < 8*S4
  int b = i / S4, r = i % S4;
  int ij = r / 576, kl = r % 576;
  float c = x[i];
  y[i] = c * (c / (amax[b * 576 + ij] + 1e-5f)) * (c / (bmax[b * 576 + kl] + 1e-5f));
}

// ---------------- K6: 4D conv, double-buffered LDS, 1 barrier/ci -----------
// block per (b-local, ij), 576 threads over (k,l). Gather map (ci-invariant)
// hoisted; ci+1 prefetched into regs during compute of ci; ping-pong halves
// so only ONE __syncthreads per ci iteration. Global-latency fully hidden
// behind the 810-FMA compute section.
template <int CIN, int COUT>
__global__ __launch_bounds__(576) void k_conv4d(
    const float* __restrict__ x, size_t xbs,
    const float* __restrict__ w, const float* __restrict__ bias,
    float* __restrict__ y, size_t ybs) {
  __shared__ float tile[2][9 * 676];          // 48.7 KB -> 3 blocks/CU
  const float* xb = x + xbs * blockIdx.y;
  float* yb = y + ybs * blockIdx.y;
  const int ij = blockIdx.x;
  const int i = ij / 24, j = ij % 24;
  const int t = threadIdx.x;
  const int k = t / 24, l = t % 24;

  // gather map: slot s covers element e = t + s*576 of the 9*676 halo tile
  int goff[11];
#pragma unroll
  for (int s = 0; s < 11; ++s) {
    int e = t + s * 576;
    int pln = e / 676, rem = e % 676;
    int di = pln / 3, dj = pln % 3;
    int kk = rem / 26 - 1, ll = rem % 26 - 1;
    int ii = i + di - 1, jj = j + dj - 1;
    bool v = (e < 6084) && ii >= 0 && ii < 24 && jj >= 0 && jj < 24 &&
             kk >= 0 && kk < 24 && ll >= 0 && ll < 24;
    goff[s] = v ? ((ii * 24 + jj) * 576 + kk * 24 + ll) : -1;
  }

  float r[11];
#pragma unroll
  for (int s = 0; s < 11; ++s)
    r[s] = (goff[s] >= 0) ? xb[goff[s]] : 0.f;
#pragma unroll
  for (int s = 0; s < 11; ++s) {
    int e = t + s * 576;
    if (e < 6084) tile[0][e] = r[s];
  }

  float acc[COUT];
#pragma unroll
  for (int co = 0; co < COUT; ++co) acc[co] = 0.f;

  for (int ci = 0; ci < CIN; ++ci) {
    const int cur = ci & 1;
    if (ci + 1 < CIN) {                       // prefetch next ci (no wait)
#pragma unroll
      for (int s = 0; s < 11; ++s)
        r[s] = (goff[s] >= 0) ? xb[(size_t)(ci + 1) * S4 + goff[s]] : 0.f;
    }
    __syncthreads();                          // tile[cur] ready
    const float* tl = tile[cur];
#pragma unroll
    for (int di = 0; di < 3; ++di)
#pragma unroll
      for (int dj = 0; dj < 3; ++dj) {
        const float* pl = &tl[(di * 3 + dj) * 676 + k * 26 + l];
        float tap[9];
#pragma unroll
        for (int dk = 0; dk < 3; ++dk)
#pragma unroll
          for (int dl = 0; dl < 3; ++dl)
            tap[dk * 3 + dl] = pl[dk * 26 + dl];
        const float* wp = w + (size_t)ci * 81 + (di * 3 + dj) * 9;
#pragma unroll
        for (int co = 0; co < COUT; ++co)
#pragma unroll
          for (int q = 0; q < 9; ++q)
            acc[co] = fmaf(tap[q], wp[(size_t)co * CIN * 81 + q], acc[co]);
      }
    if (ci + 1 < CIN) {                       // write prefetched into other half
#pragma unroll
      for (int s = 0; s < 11; ++s) {
        int e = t + s * 576;
        if (e < 6084) tile[cur ^ 1][e] = r[s];
      }
    }
  }
#pragma unroll
  for (int co = 0; co < COUT; ++co) {
    float v = fmaxf(acc[co] + bias[co], 0.f);
    yb[(size_t)co * S4 + (size_t)ij * 576 + t] = v;
  }
}

// ---------------------------------------------------------------------------
extern "C" void kernel_launch(void* const* d_in, const int* in_sizes, int n_in,
                              void* d_out, int out_size, void* d_ws, size_t ws_size,
                              hipStream_t stream) {
  const float* fA = (const float*)d_in[0];
  const float* fB = (const float*)d_in[1];
  const float* w1 = (const float*)d_in[2];
  const float* b1 = (const float*)d_in[3];
  const float* w2 = (const float*)d_in[4];
  const float* b2 = (const float*)d_in[5];
  const float* w3 = (const float*)d_in[6];
  const float* b3 = (const float*)d_in[7];
  float* out = (float*)d_out;

  float* ws = (float*)d_ws;
  size_t off = 0;
  auto alloc = [&](size_t n) {
    float* p = ws + off;
    off += (n + 63) & ~(size_t)63;
    return p;
  };
  float* pooled = alloc((size_t)8 * S4);
  float* C3     = alloc((size_t)8 * S4);
  float* part   = alloc((size_t)2 * 16 * P_);
  float* invn   = alloc((size_t)16 * P_);
  float* amax1  = alloc(8 * 576);
  float* bmax1  = alloc(8 * 576);
  float* amax2  = alloc(8 * 576);
  float* bmax2  = alloc(8 * 576);

  // batch-group size G for the conv chain: C1/C2 hold G batches each.
  // ws_size is fixed across calls -> branch is graph-capture-safe.
  const size_t t_floats = (size_t)2 * P_ * C_;          // T overlay (bf16 x4)
  int G = 1;
  for (int g = 8; g > 1; g >>= 1) {
    size_t xf = (size_t)20 * S4 * g;
    size_t need = (off + (xf > t_floats ? xf : t_floats) + 64) * 4;
    if (need <= ws_size) { G = g; break; }
  }
  size_t xf = (size_t)20 * S4 * G;
  float* X = alloc(xf > t_floats ? xf : t_floats);
  float* C1 = X;
  float* C2 = X + (size_t)10 * S4 * G;
  unsigned short* TAhi = (unsigned short*)X;
  unsigned short* TAlo = TAhi + (size_t)P_ * C_;
  unsigned short* TBhi = TAlo + (size_t)P_ * C_;
  unsigned short* TBlo = TBhi + (size_t)P_ * C_;
  (void)in_sizes; (void)n_in; (void)out_size;

  // 1+2) per-batch: transpose/split + norms + MFMA correlation
  for (int b = 0; b < 8; ++b) {
    k_prep<<<dim3(16, 36, 2), 256, 0, stream>>>(fA, fB, b, TAhi, TAlo, TBhi, TBlo, part);
    k_invnorm<<<dim3(9, 2), 256, 0, stream>>>(part, invn, b);
    k_corr_mfma<<<dim3(576), 256, 0, stream>>>(TAhi, TAlo, TBhi, TBlo, invn, b,
                                               pooled + (size_t)b * S4);
  }

  // 3) mutual matching #1 (in place)
  k_rowmax<<<dim3(8 * 576), 64, 0, stream>>>(pooled, amax1);
  k_colmax<<<dim3(8, 9), 256, 0, stream>>>(pooled, bmax1);
  k_mm_apply<<<dim3(10368), 256, 0, stream>>>(pooled, amax1, bmax1, pooled);

  // 4) neighbourhood consensus: 3x conv4d + relu, G batches per dispatch
  for (int b0 = 0; b0 < 8; b0 += G) {
    k_conv4d<1, 10><<<dim3(576, G), 576, 0, stream>>>(
        pooled + (size_t)b0 * S4, (size_t)S4, w1, b1, C1, (size_t)10 * S4);
    k_conv4d<10, 10><<<dim3(576, G), 576, 0, stream>>>(
        C1, (size_t)10 * S4, w2, b2, C2, (size_t)10 * S4);
    k_conv4d<10, 1><<<dim3(576, G), 576, 0, stream>>>(
        C2, (size_t)10 * S4, w3, b3, C3 + (size_t)b0 * S4, (size_t)S4);
  }

  // 5) mutual matching #2 -> final output
  k_rowmax<<<dim3(8 * 576), 64, 0, stream>>>(C3, amax2);
  k_colmax<<<dim3(8, 9), 256, 0, stream>>>(C3, bmax2);
  k_mm_apply<<<dim3(10368), 256, 0, stream>>>(C3, amax2, bmax2, out);
}

// Round 4
// 3226.597 us; speedup vs baseline: 1.7785x; 1.7785x over previous
//
#include <hip/hip_runtime.h>
#include <hip/hip_bf16.h>
#include <math.h>

#define C_   1024
#define P_   2304      // 48*48
#define S4   331776    // 24^4

typedef __attribute__((ext_vector_type(8))) short short8;
typedef __attribute__((ext_vector_type(4))) float f32x4;

__device__ inline unsigned short f2bf(float v) {
  unsigned u = __builtin_bit_cast(unsigned, v);
  u += 0x7fffu + ((u >> 16) & 1u);          // RNE
  return (unsigned short)(u >> 16);
}
__device__ inline float bf2f(unsigned short h) {
  unsigned u = ((unsigned)h) << 16;
  return __builtin_bit_cast(float, u);
}

// ---------------- K1: transpose + bf16 hi/lo split + sumsq partials --------
// grid (16 ctiles, 36 ptiles, 16 fb); fb = f*8 + b.
__global__ __launch_bounds__(256) void k_prep(
    const float* __restrict__ fA, const float* __restrict__ fB,
    unsigned short* __restrict__ TAhi, unsigned short* __restrict__ TAlo,
    unsigned short* __restrict__ TBhi, unsigned short* __restrict__ TBlo,
    float* __restrict__ part) {
  __shared__ float ld[64 * 65];
  __shared__ float pslds[512];
  const int c0 = blockIdx.x * 64, p0 = blockIdx.y * 64;
  const int fb = blockIdx.z, f = fb >> 3, b = fb & 7;
  const float* src = (f ? fB : fA) + (size_t)b * C_ * P_;
  unsigned short* Thi = (f ? TBhi : TAhi) + (size_t)b * P_ * C_;
  unsigned short* Tlo = (f ? TBlo : TAlo) + (size_t)b * P_ * C_;
  const int t = threadIdx.x;
#pragma unroll
  for (int e = 0; e < 4; ++e) {
    int cid = t + e * 256;                  // 0..1023
    int r = cid >> 4, ch = cid & 15;
    float4 v = *(const float4*)&src[(size_t)(c0 + r) * P_ + p0 + ch * 4];
    ld[r * 65 + ch * 4 + 0] = v.x;
    ld[r * 65 + ch * 4 + 1] = v.y;
    ld[r * 65 + ch * 4 + 2] = v.z;
    ld[r * 65 + ch * 4 + 3] = v.w;
  }
  __syncthreads();
#pragma unroll
  for (int e = 0; e < 2; ++e) {
    int ocid = t + e * 256;                 // 0..511
    int pl = ocid >> 3, c8 = ocid & 7;
    unsigned short hi[8], lo[8];
    float sq = 0.f;
#pragma unroll
    for (int s = 0; s < 8; ++s) {
      float v = ld[(c8 * 8 + s) * 65 + pl];
      unsigned short h = f2bf(v);
      float rem = v - bf2f(h);
      hi[s] = h; lo[s] = f2bf(rem);
      sq = fmaf(v, v, sq);
    }
    size_t go = (size_t)(p0 + pl) * C_ + c0 + c8 * 8;
    *(uint4*)&Thi[go] = *(uint4*)hi;
    *(uint4*)&Tlo[go] = *(uint4*)lo;
    pslds[ocid] = sq;
  }
  __syncthreads();
  if (t < 64) {
    float s = 0.f;
#pragma unroll
    for (int c8 = 0; c8 < 8; ++c8) s += pslds[t * 8 + c8];
    part[((size_t)fb * 16 + blockIdx.x) * P_ + p0 + t] = s;
  }
}

// ---------------- K2: finalize inverse norms -------------------------------
__global__ void k_invnorm(const float* __restrict__ part, float* __restrict__ inv) {
  int p = blockIdx.x * 256 + threadIdx.x;
  int fb = blockIdx.y;
  float s = 1e-6f;
  for (int ct = 0; ct < 16; ++ct) s += part[((size_t)fb * 16 + ct) * P_ + p];
  inv[(size_t)fb * P_ + p] = 1.0f / sqrtf(s);
}

// ---------------- K3: bf16x3 MFMA correlation + relu/norm/4D-maxpool -------
// grid (576 tiles, 8 batches)
__global__ __launch_bounds__(256) void k_corr_mfma(
    const unsigned short* __restrict__ TAhi_, const unsigned short* __restrict__ TAlo_,
    const unsigned short* __restrict__ TBhi_, const unsigned short* __restrict__ TBlo_,
    const float* __restrict__ invn, float* __restrict__ pooled) {
  __shared__ __align__(16) char lds_raw[37248];
  unsigned short* stage = (unsigned short*)lds_raw;   // 4 arrays of 96x40
  float* epi = (float*)lds_raw;                       // 96x97 f32 overlay

  const int b = blockIdx.y;
  const size_t tb = (size_t)b * P_ * C_;
  const unsigned short* TAhi = TAhi_ + tb;
  const unsigned short* TAlo = TAlo_ + tb;
  const unsigned short* TBhi = TBhi_ + tb;
  const unsigned short* TBlo = TBlo_ + tb;
  float* out = pooled + (size_t)b * S4;

  const int ti = blockIdx.x / 24, tj = blockIdx.x % 24;
  const int p0 = ti * 96, q0 = tj * 96;
  const int t = threadIdx.x;
  const int lane = t & 63, w = t >> 6;
  const int wr = w >> 1, wc = w & 1;
  const int m15 = lane & 15, q4 = lane >> 4;
  const int koff = q4 * 8;

  f32x4 acc[3][3];
#pragma unroll
  for (int a = 0; a < 3; ++a)
#pragma unroll
    for (int c = 0; c < 3; ++c) acc[a][c] = (f32x4){0.f, 0.f, 0.f, 0.f};

  uint4 pre[6];
  const unsigned short* gsrc[6];
  int ldsoff[6];
#pragma unroll
  for (int e = 0; e < 6; ++e) {
    int cid = t + e * 256;                 // 0..1535
    int arr = cid / 384, wi = cid % 384;
    int rr = wi >> 2, kc = wi & 3;
    const unsigned short* base = (arr == 0) ? TAhi : (arr == 1) ? TAlo
                               : (arr == 2) ? TBhi : TBlo;
    int pb = (arr < 2) ? p0 : q0;
    gsrc[e] = base + (size_t)(pb + rr) * C_ + kc * 8;
    ldsoff[e] = arr * 3840 + rr * 40 + kc * 8;
  }
#pragma unroll
  for (int e = 0; e < 6; ++e) pre[e] = *(const uint4*)(gsrc[e]);   // kt=0

  for (int kt = 0; kt < C_; kt += 32) {
    __syncthreads();
#pragma unroll
    for (int e = 0; e < 6; ++e) *(uint4*)&stage[ldsoff[e]] = pre[e];
    __syncthreads();
    if (kt + 32 < C_) {
#pragma unroll
      for (int e = 0; e < 6; ++e) pre[e] = *(const uint4*)(gsrc[e] + kt + 32);
    }
    const unsigned short* Ah = stage;
    const unsigned short* Al = stage + 3840;
    const unsigned short* Bh = stage + 7680;
    const unsigned short* Bl = stage + 11520;
    short8 ah[3], al[3], bh[3], bl[3];
#pragma unroll
    for (int a = 0; a < 3; ++a) {
      int row = wr * 48 + a * 16 + m15;
      ah[a] = *(const short8*)&Ah[row * 40 + koff];
      al[a] = *(const short8*)&Al[row * 40 + koff];
    }
#pragma unroll
    for (int c = 0; c < 3; ++c) {
      int row = wc * 48 + c * 16 + m15;
      bh[c] = *(const short8*)&Bh[row * 40 + koff];
      bl[c] = *(const short8*)&Bl[row * 40 + koff];
    }
#pragma unroll
    for (int a = 0; a < 3; ++a)
#pragma unroll
      for (int c = 0; c < 3; ++c)
        acc[a][c] = __builtin_amdgcn_mfma_f32_16x16x32_bf16(ah[a], bh[c], acc[a][c], 0, 0, 0);
#pragma unroll
    for (int a = 0; a < 3; ++a)
#pragma unroll
      for (int c = 0; c < 3; ++c)
        acc[a][c] = __builtin_amdgcn_mfma_f32_16x16x32_bf16(ah[a], bl[c], acc[a][c], 0, 0, 0);
#pragma unroll
    for (int a = 0; a < 3; ++a)
#pragma unroll
      for (int c = 0; c < 3; ++c)
        acc[a][c] = __builtin_amdgcn_mfma_f32_16x16x32_bf16(al[a], bh[c], acc[a][c], 0, 0, 0);
  }
  __syncthreads();

  const float* invA = invn + (size_t)b * P_;
  const float* invB = invn + (size_t)(8 + b) * P_;
  float ib[3];
#pragma unroll
  for (int c = 0; c < 3; ++c) ib[c] = invB[q0 + wc * 48 + c * 16 + m15];
#pragma unroll
  for (int a = 0; a < 3; ++a) {
#pragma unroll
    for (int reg = 0; reg < 4; ++reg) {
      int pl = wr * 48 + a * 16 + q4 * 4 + reg;
      float ia = invA[p0 + pl];
#pragma unroll
      for (int c = 0; c < 3; ++c) {
        int ql = wc * 48 + c * 16 + m15;
        epi[pl * 97 + ql] = acc[a][c][reg] * ia * ib[c];
      }
    }
  }
  __syncthreads();

  for (int idx = t; idx < 576; idx += 256) {
    int j = idx / 24, l = idx % 24;
    float m = -1e30f;
#pragma unroll
    for (int dh = 0; dh < 2; ++dh)
#pragma unroll
      for (int dw = 0; dw < 2; ++dw) {
        int row = dh * 48 + 2 * j + dw;
#pragma unroll
        for (int d2 = 0; d2 < 2; ++d2)
#pragma unroll
          for (int dw2 = 0; dw2 < 2; ++dw2)
            m = fmaxf(m, epi[row * 97 + d2 * 48 + 2 * l + dw2]);
      }
    float r = fmaxf(m, 0.f);
    float v = r / sqrtf(r * r + 1e-6f);
    out[(size_t)(ti * 24 + j) * 576 + tj * 24 + l] = v;
  }
}

// ---------------- K4a: row max (over kl, per ij) ---------------------------
__global__ void k_rowmax(const float* __restrict__ x, float* __restrict__ amax) {
  int row = blockIdx.x;                       // b*576 + ij
  const float* r = x + (size_t)row * 576;
  float m = -1e30f;
  for (int e = threadIdx.x; e < 576; e += 64) m = fmaxf(m, r[e]);
  for (int off = 32; off > 0; off >>= 1) m = fmaxf(m, __shfl_down(m, off, 64));
  if (threadIdx.x == 0) amax[row] = m;
}

// ---------------- K4b: col max (over ij, per kl) ---------------------------
__global__ void k_colmax(const float* __restrict__ x, float* __restrict__ bmax) {
  __shared__ float pl[4][64];
  int b = blockIdx.x, klc = blockIdx.y * 64;
  int t = threadIdx.x;
  int kl = klc + (t & 63), seg = t >> 6;
  const float* xb = x + (size_t)b * S4;
  float m = -1e30f;
  for (int ij = seg * 144; ij < (seg + 1) * 144; ++ij)
    m = fmaxf(m, xb[(size_t)ij * 576 + kl]);
  pl[seg][t & 63] = m;
  __syncthreads();
  if (t < 64) {
    float r = fmaxf(fmaxf(pl[0][t], pl[1][t]), fmaxf(pl[2][t], pl[3][t]));
    bmax[b * 576 + klc + t] = r;
  }
}

// ---------------- K5: mutual matching elementwise --------------------------
__global__ void k_mm_apply(const float* __restrict__ x,
                           const float* __restrict__ amax,
                           const float* __restrict__ bmax,
                           float* __restrict__ y) {
  int i = blockIdx.x * 256 + threadIdx.x;     // < 8*S4
  int b = i / S4, r = i % S4;
  int ij = r / 576, kl = r % 576;
  float c = x[i];
  y[i] = c * (c / (amax[b * 576 + ij] + 1e-5f)) * (c / (bmax[b * 576 + kl] + 1e-5f));
}

// ---------------- K6: 4D conv — 192 thr, 3 outputs/thread, high occupancy --
// Block = one (i,j), full (k,l) plane; thread owns (k, l0..l0+2).
// LDS: 9 slabs, 26 rows x 27-stride (halo + conflict-free stride) = 25.3 KB
// -> 6 blocks/CU (18 waves). Taps read as 5-wide row windows (ds_read2-
// mergeable), each serving 3 outputs: LDS issue ~1/10 of VALU issue.
template <int CIN, int COUT>
__global__ __launch_bounds__(192) void k_conv4d(
    const float* __restrict__ x, size_t xbs,
    const float* __restrict__ w, const float* __restrict__ bias,
    float* __restrict__ y, size_t ybs) {
  __shared__ float tile[9 * 702];             // 702 = 26 rows * 27
  const float* xb = x + xbs * blockIdx.y;
  float* yb = y + ybs * blockIdx.y;
  const int ij = blockIdx.x;
  const int i = ij / 24, j = ij % 24;
  const int t = threadIdx.x;                  // 0..191
  const int k = t >> 3;                       // 0..23
  const int l0 = (t & 7) * 3;                 // 0,3,..,21

  // staging map (ci-invariant): 702 elems per plane, 4 passes of 192
  int soff[4]; bool eok[4], klok[4]; int eidx[4];
#pragma unroll
  for (int q = 0; q < 4; ++q) {
    int e = t + q * 192;
    eidx[q] = e; eok[q] = (e < 702);
    int row = e / 27, col = e % 27;           // halo coords
    klok[q] = (row >= 1 && row < 25 && col >= 1 && col < 25);
    soff[q] = (row - 1) * 24 + (col - 1);
  }

  float acc[COUT][3];
#pragma unroll
  for (int co = 0; co < COUT; ++co)
#pragma unroll
    for (int oo = 0; oo < 3; ++oo) acc[co][oo] = 0.f;

  for (int ci = 0; ci < CIN; ++ci) {
    __syncthreads();                          // previous compute done
#pragma unroll
    for (int pln = 0; pln < 9; ++pln) {
      int ii = i + pln / 3 - 1, jj = j + pln % 3 - 1;
      const bool slab_ok = (ii >= 0 && ii < 24 && jj >= 0 && jj < 24); // uniform
      const float* src = xb + (size_t)ci * S4 + (size_t)(ii * 24 + jj) * 576;
#pragma unroll
      for (int q = 0; q < 4; ++q) {
        if (eok[q]) {
          float v = 0.f;
          if (slab_ok && klok[q]) v = src[soff[q]];
          tile[pln * 702 + eidx[q]] = v;
        }
      }
    }
    __syncthreads();
#pragma unroll
    for (int pln = 0; pln < 9; ++pln) {
      const float* base = &tile[pln * 702 + k * 27 + l0];
#pragma unroll
      for (int dk = 0; dk < 3; ++dk) {
        float c0 = base[dk * 27 + 0], c1 = base[dk * 27 + 1],
              c2 = base[dk * 27 + 2], c3 = base[dk * 27 + 3],
              c4 = base[dk * 27 + 4];
#pragma unroll
        for (int co = 0; co < COUT; ++co) {
          const float* wr = w + ((size_t)co * CIN + ci) * 81 + pln * 9 + dk * 3;
          float w0 = wr[0], w1 = wr[1], w2 = wr[2];
          acc[co][0] = fmaf(w0, c0, acc[co][0]);
          acc[co][0] = fmaf(w1, c1, acc[co][0]);
          acc[co][0] = fmaf(w2, c2, acc[co][0]);
          acc[co][1] = fmaf(w0, c1, acc[co][1]);
          acc[co][1] = fmaf(w1, c2, acc[co][1]);
          acc[co][1] = fmaf(w2, c3, acc[co][1]);
          acc[co][2] = fmaf(w0, c2, acc[co][2]);
          acc[co][2] = fmaf(w1, c3, acc[co][2]);
          acc[co][2] = fmaf(w2, c4, acc[co][2]);
        }
      }
    }
  }
#pragma unroll
  for (int co = 0; co < COUT; ++co) {
    float bv = bias[co];
#pragma unroll
    for (int oo = 0; oo < 3; ++oo) {
      float v = fmaxf(acc[co][oo] + bv, 0.f);
      yb[(size_t)co * S4 + (size_t)ij * 576 + k * 24 + l0 + oo] = v;
    }
  }
}

// ---------------------------------------------------------------------------
extern "C" void kernel_launch(void* const* d_in, const int* in_sizes, int n_in,
                              void* d_out, int out_size, void* d_ws, size_t ws_size,
                              hipStream_t stream) {
  const float* fA = (const float*)d_in[0];
  const float* fB = (const float*)d_in[1];
  const float* w1 = (const float*)d_in[2];
  const float* b1 = (const float*)d_in[3];
  const float* w2 = (const float*)d_in[4];
  const float* b2 = (const float*)d_in[5];
  const float* w3 = (const float*)d_in[6];
  const float* b3 = (const float*)d_in[7];
  float* out = (float*)d_out;

  float* ws = (float*)d_ws;
  size_t off = 0;
  auto alloc = [&](size_t n) {
    float* p = ws + off;
    off += (n + 63) & ~(size_t)63;
    return p;
  };
  float* pooled = alloc((size_t)8 * S4);          // 10.6 MB
  float* C3     = alloc((size_t)8 * S4);          // 10.6 MB
  float* part   = alloc((size_t)16 * 16 * P_);    // 2.4 MB
  float* invn   = alloc((size_t)16 * P_);
  float* amax1  = alloc(8 * 576);
  float* bmax1  = alloc(8 * 576);
  float* amax2  = alloc(8 * 576);
  float* bmax2  = alloc(8 * 576);
  // X: conv C1+C2 (20*S4*8 floats = 212 MB) overlays the T arrays (151 MB).
  // R3 ran with identical footprint -> ws_size is sufficient.
  float* X = alloc((size_t)20 * S4 * 8);
  float* C1 = X;
  float* C2 = X + (size_t)10 * S4 * 8;
  unsigned short* TAhi = (unsigned short*)X;      // each 8*P_*C_ ushorts
  unsigned short* TAlo = TAhi + (size_t)8 * P_ * C_;
  unsigned short* TBhi = TAlo + (size_t)8 * P_ * C_;
  unsigned short* TBlo = TBhi + (size_t)8 * P_ * C_;
  (void)in_sizes; (void)n_in; (void)out_size; (void)ws_size;

  // 1+2) transpose/split + norms + MFMA correlation — all batches per dispatch
  k_prep<<<dim3(16, 36, 16), 256, 0, stream>>>(fA, fB, TAhi, TAlo, TBhi, TBlo, part);
  k_invnorm<<<dim3(9, 16), 256, 0, stream>>>(part, invn);
  k_corr_mfma<<<dim3(576, 8), 256, 0, stream>>>(TAhi, TAlo, TBhi, TBlo, invn, pooled);

  // 3) mutual matching #1 (in place)
  k_rowmax<<<dim3(8 * 576), 64, 0, stream>>>(pooled, amax1);
  k_colmax<<<dim3(8, 9), 256, 0, stream>>>(pooled, bmax1);
  k_mm_apply<<<dim3(10368), 256, 0, stream>>>(pooled, amax1, bmax1, pooled);

  // 4) neighbourhood consensus: 3x conv4d + relu, all batches per dispatch
  k_conv4d<1, 10><<<dim3(576, 8), 192, 0, stream>>>(
      pooled, (size_t)S4, w1, b1, C1, (size_t)10 * S4);
  k_conv4d<10, 10><<<dim3(576, 8), 192, 0, stream>>>(
      C1, (size_t)10 * S4, w2, b2, C2, (size_t)10 * S4);
  k_conv4d<10, 1><<<dim3(576, 8), 192, 0, stream>>>(
      C2, (size_t)10 * S4, w3, b3, C3, (size_t)S4);

  // 5) mutual matching #2 -> final output
  k_rowmax<<<dim3(8 * 576), 64, 0, stream>>>(C3, amax2);
  k_colmax<<<dim3(8, 9), 256, 0, stream>>>(C3, bmax2);
  k_mm_apply<<<dim3(10368), 256, 0, stream>>>(C3, amax2, bmax2, out);
}

// Round 5
// 2724.414 us; speedup vs baseline: 2.1063x; 1.1843x over previous
//
#include <hip/hip_runtime.h>
#include <hip/hip_bf16.h>
#include <math.h>

#define C_   1024
#define P_   2304      // 48*48
#define S4   331776    // 24^4

typedef __attribute__((ext_vector_type(8))) short short8;
typedef __attribute__((ext_vector_type(4))) float f32x4;

__device__ inline unsigned short f2bf(float v) {
  unsigned u = __builtin_bit_cast(unsigned, v);
  u += 0x7fffu + ((u >> 16) & 1u);          // RNE
  return (unsigned short)(u >> 16);
}
__device__ inline float bf2f(unsigned short h) {
  unsigned u = ((unsigned)h) << 16;
  return __builtin_bit_cast(float, u);
}

// ---------------- K1: transpose + bf16 hi/lo split + sumsq partials --------
// grid (16 ctiles, 36 ptiles, 16 fb); fb = f*8 + b.
__global__ __launch_bounds__(256) void k_prep(
    const float* __restrict__ fA, const float* __restrict__ fB,
    unsigned short* __restrict__ TAhi, unsigned short* __restrict__ TAlo,
    unsigned short* __restrict__ TBhi, unsigned short* __restrict__ TBlo,
    float* __restrict__ part) {
  __shared__ float ld[64 * 65];
  __shared__ float pslds[512];
  const int c0 = blockIdx.x * 64, p0 = blockIdx.y * 64;
  const int fb = blockIdx.z, f = fb >> 3, b = fb & 7;
  const float* src = (f ? fB : fA) + (size_t)b * C_ * P_;
  unsigned short* Thi = (f ? TBhi : TAhi) + (size_t)b * P_ * C_;
  unsigned short* Tlo = (f ? TBlo : TAlo) + (size_t)b * P_ * C_;
  const int t = threadIdx.x;
#pragma unroll
  for (int e = 0; e < 4; ++e) {
    int cid = t + e * 256;                  // 0..1023
    int r = cid >> 4, ch = cid & 15;
    float4 v = *(const float4*)&src[(size_t)(c0 + r) * P_ + p0 + ch * 4];
    ld[r * 65 + ch * 4 + 0] = v.x;
    ld[r * 65 + ch * 4 + 1] = v.y;
    ld[r * 65 + ch * 4 + 2] = v.z;
    ld[r * 65 + ch * 4 + 3] = v.w;
  }
  __syncthreads();
#pragma unroll
  for (int e = 0; e < 2; ++e) {
    int ocid = t + e * 256;                 // 0..511
    int pl = ocid >> 3, c8 = ocid & 7;
    unsigned short hi[8], lo[8];
    float sq = 0.f;
#pragma unroll
    for (int s = 0; s < 8; ++s) {
      float v = ld[(c8 * 8 + s) * 65 + pl];
      unsigned short h = f2bf(v);
      float rem = v - bf2f(h);
      hi[s] = h; lo[s] = f2bf(rem);
      sq = fmaf(v, v, sq);
    }
    size_t go = (size_t)(p0 + pl) * C_ + c0 + c8 * 8;
    *(uint4*)&Thi[go] = *(uint4*)hi;
    *(uint4*)&Tlo[go] = *(uint4*)lo;
    pslds[ocid] = sq;
  }
  __syncthreads();
  if (t < 64) {
    float s = 0.f;
#pragma unroll
    for (int c8 = 0; c8 < 8; ++c8) s += pslds[t * 8 + c8];
    part[((size_t)fb * 16 + blockIdx.x) * P_ + p0 + t] = s;
  }
}

// ---------------- K2: finalize inverse norms -------------------------------
__global__ void k_invnorm(const float* __restrict__ part, float* __restrict__ inv) {
  int p = blockIdx.x * 256 + threadIdx.x;
  int fb = blockIdx.y;
  float s = 1e-6f;
  for (int ct = 0; ct < 16; ++ct) s += part[((size_t)fb * 16 + ct) * P_ + p];
  inv[(size_t)fb * P_ + p] = 1.0f / sqrtf(s);
}

// ---------------- K3: bf16x3 MFMA correlation + relu/norm/4D-maxpool -------
// grid (576 tiles, 8 batches). launch_bounds(256,2): 256-VGPR budget -> the
// ~166-reg live set (frags 48 + pre 24 + acc 36 + addr) fits with NO scratch
// spills (R4: default cap gave VGPR=60 and 2.6 GB/dispatch spill traffic).
__global__ __launch_bounds__(256, 2) void k_corr_mfma(
    const unsigned short* __restrict__ TAhi_, const unsigned short* __restrict__ TAlo_,
    const unsigned short* __restrict__ TBhi_, const unsigned short* __restrict__ TBlo_,
    const float* __restrict__ invn, float* __restrict__ pooled) {
  __shared__ __align__(16) char lds_raw[37248];
  unsigned short* stage = (unsigned short*)lds_raw;   // 4 arrays of 96x40
  float* epi = (float*)lds_raw;                       // 96x97 f32 overlay

  const int b = blockIdx.y;
  const size_t tb = (size_t)b * P_ * C_;
  const unsigned short* TAhi = TAhi_ + tb;
  const unsigned short* TAlo = TAlo_ + tb;
  const unsigned short* TBhi = TBhi_ + tb;
  const unsigned short* TBlo = TBlo_ + tb;
  float* out = pooled + (size_t)b * S4;

  // XCD-rect swizzle: xcd = g%8 owns a 6x12 (ti,tj) rectangle -> its L2
  // revisits 18 strips instead of 48. 576%8==0 keeps batches aligned.
  const int g = blockIdx.x;
  const int xcd = g & 7, idx = g >> 3;                // idx 0..71
  const int ti = (xcd & 3) * 6 + idx / 12;
  const int tj = (xcd >> 2) * 12 + idx % 12;
  const int p0 = ti * 96, q0 = tj * 96;
  const int t = threadIdx.x;
  const int lane = t & 63, w = t >> 6;
  const int wr = w >> 1, wc = w & 1;
  const int m15 = lane & 15, q4 = lane >> 4;
  const int koff = q4 * 8;

  f32x4 acc[3][3];
#pragma unroll
  for (int a = 0; a < 3; ++a)
#pragma unroll
    for (int c = 0; c < 3; ++c) acc[a][c] = (f32x4){0.f, 0.f, 0.f, 0.f};

  uint4 pre[6];
  const unsigned short* gsrc[6];
  int ldsoff[6];
#pragma unroll
  for (int e = 0; e < 6; ++e) {
    int cid = t + e * 256;                 // 0..1535
    int arr = cid / 384, wi = cid % 384;
    int rr = wi >> 2, kc = wi & 3;
    const unsigned short* base = (arr == 0) ? TAhi : (arr == 1) ? TAlo
                               : (arr == 2) ? TBhi : TBlo;
    int pb = (arr < 2) ? p0 : q0;
    gsrc[e] = base + (size_t)(pb + rr) * C_ + kc * 8;
    ldsoff[e] = arr * 3840 + rr * 40 + kc * 8;
  }
#pragma unroll
  for (int e = 0; e < 6; ++e) pre[e] = *(const uint4*)(gsrc[e]);   // kt=0

  for (int kt = 0; kt < C_; kt += 32) {
    __syncthreads();
#pragma unroll
    for (int e = 0; e < 6; ++e) *(uint4*)&stage[ldsoff[e]] = pre[e];
    __syncthreads();
    if (kt + 32 < C_) {
#pragma unroll
      for (int e = 0; e < 6; ++e) pre[e] = *(const uint4*)(gsrc[e] + kt + 32);
    }
    const unsigned short* Ah = stage;
    const unsigned short* Al = stage + 3840;
    const unsigned short* Bh = stage + 7680;
    const unsigned short* Bl = stage + 11520;
    short8 ah[3], al[3], bh[3], bl[3];
#pragma unroll
    for (int a = 0; a < 3; ++a) {
      int row = wr * 48 + a * 16 + m15;
      ah[a] = *(const short8*)&Ah[row * 40 + koff];
      al[a] = *(const short8*)&Al[row * 40 + koff];
    }
#pragma unroll
    for (int c = 0; c < 3; ++c) {
      int row = wc * 48 + c * 16 + m15;
      bh[c] = *(const short8*)&Bh[row * 40 + koff];
      bl[c] = *(const short8*)&Bl[row * 40 + koff];
    }
#pragma unroll
    for (int a = 0; a < 3; ++a)
#pragma unroll
      for (int c = 0; c < 3; ++c)
        acc[a][c] = __builtin_amdgcn_mfma_f32_16x16x32_bf16(ah[a], bh[c], acc[a][c], 0, 0, 0);
#pragma unroll
    for (int a = 0; a < 3; ++a)
#pragma unroll
      for (int c = 0; c < 3; ++c)
        acc[a][c] = __builtin_amdgcn_mfma_f32_16x16x32_bf16(ah[a], bl[c], acc[a][c], 0, 0, 0);
#pragma unroll
    for (int a = 0; a < 3; ++a)
#pragma unroll
      for (int c = 0; c < 3; ++c)
        acc[a][c] = __builtin_amdgcn_mfma_f32_16x16x32_bf16(al[a], bh[c], acc[a][c], 0, 0, 0);
  }
  __syncthreads();

  const float* invA = invn + (size_t)b * P_;
  const float* invB = invn + (size_t)(8 + b) * P_;
  float ib[3];
#pragma unroll
  for (int c = 0; c < 3; ++c) ib[c] = invB[q0 + wc * 48 + c * 16 + m15];
#pragma unroll
  for (int a = 0; a < 3; ++a) {
#pragma unroll
    for (int reg = 0; reg < 4; ++reg) {
      int pl = wr * 48 + a * 16 + q4 * 4 + reg;
      float ia = invA[p0 + pl];
#pragma unroll
      for (int c = 0; c < 3; ++c) {
        int ql = wc * 48 + c * 16 + m15;
        epi[pl * 97 + ql] = acc[a][c][reg] * ia * ib[c];
      }
    }
  }
  __syncthreads();

  for (int idx2 = t; idx2 < 576; idx2 += 256) {
    int j = idx2 / 24, l = idx2 % 24;
    float m = -1e30f;
#pragma unroll
    for (int dh = 0; dh < 2; ++dh)
#pragma unroll
      for (int dw = 0; dw < 2; ++dw) {
        int row = dh * 48 + 2 * j + dw;
#pragma unroll
        for (int d2 = 0; d2 < 2; ++d2)
#pragma unroll
          for (int dw2 = 0; dw2 < 2; ++dw2)
            m = fmaxf(m, epi[row * 97 + d2 * 48 + 2 * l + dw2]);
      }
    float r = fmaxf(m, 0.f);
    float v = r / sqrtf(r * r + 1e-6f);
    out[(size_t)(ti * 24 + j) * 576 + tj * 24 + l] = v;
  }
}

// ---------------- K4a: row max (over kl, per ij) ---------------------------
__global__ void k_rowmax(const float* __restrict__ x, float* __restrict__ amax) {
  int row = blockIdx.x;                       // b*576 + ij
  const float* r = x + (size_t)row * 576;
  float m = -1e30f;
  for (int e = threadIdx.x; e < 576; e += 64) m = fmaxf(m, r[e]);
  for (int off = 32; off > 0; off >>= 1) m = fmaxf(m, __shfl_down(m, off, 64));
  if (threadIdx.x == 0) amax[row] = m;
}

// ---------------- K4b: col max (over ij, per kl) ---------------------------
__global__ void k_colmax(const float* __restrict__ x, float* __restrict__ bmax) {
  __shared__ float pl[4][64];
  int b = blockIdx.x, klc = blockIdx.y * 64;
  int t = threadIdx.x;
  int kl = klc + (t & 63), seg = t >> 6;
  const float* xb = x + (size_t)b * S4;
  float m = -1e30f;
  for (int ij = seg * 144; ij < (seg + 1) * 144; ++ij)
    m = fmaxf(m, xb[(size_t)ij * 576 + kl]);
  pl[seg][t & 63] = m;
  __syncthreads();
  if (t < 64) {
    float r = fmaxf(fmaxf(pl[0][t], pl[1][t]), fmaxf(pl[2][t], pl[3][t]));
    bmax[b * 576 + klc + t] = r;
  }
}

// ---------------- K5: mutual matching elementwise --------------------------
__global__ void k_mm_apply(const float* __restrict__ x,
                           const float* __restrict__ amax,
                           const float* __restrict__ bmax,
                           float* __restrict__ y) {
  int i = blockIdx.x * 256 + threadIdx.x;     // < 8*S4
  int b = i / S4, r = i % S4;
  int ij = r / 576, kl = r % 576;
  float c = x[i];
  y[i] = c * (c / (amax[b * 576 + ij] + 1e-5f)) * (c / (bmax[b * 576 + kl] + 1e-5f));
}

// ---------------- K6: 4D conv — 192 thr, 3 outputs/thread ------------------
// launch_bounds(192,4): 128-VGPR budget (need ~70-90) -> no spill risk while
// keeping 16 waves/CU. LDS 25.3 KB -> 5 blocks/CU.
template <int CIN, int COUT>
__global__ __launch_bounds__(192, 4) void k_conv4d(
    const float* __restrict__ x, size_t xbs,
    const float* __restrict__ w, const float* __restrict__ bias,
    float* __restrict__ y, size_t ybs) {
  __shared__ float tile[9 * 702];             // 702 = 26 rows * 27
  const float* xb = x + xbs * blockIdx.y;
  float* yb = y + ybs * blockIdx.y;
  const int ij = blockIdx.x;
  const int i = ij / 24, j = ij % 24;
  const int t = threadIdx.x;                  // 0..191
  const int k = t >> 3;                       // 0..23
  const int l0 = (t & 7) * 3;                 // 0,3,..,21

  int soff[4]; bool eok[4], klok[4]; int eidx[4];
#pragma unroll
  for (int q = 0; q < 4; ++q) {
    int e = t + q * 192;
    eidx[q] = e; eok[q] = (e < 702);
    int row = e / 27, col = e % 27;           // halo coords
    klok[q] = (row >= 1 && row < 25 && col >= 1 && col < 25);
    soff[q] = (row - 1) * 24 + (col - 1);
  }

  float acc[COUT][3];
#pragma unroll
  for (int co = 0; co < COUT; ++co)
#pragma unroll
    for (int oo = 0; oo < 3; ++oo) acc[co][oo] = 0.f;

  for (int ci = 0; ci < CIN; ++ci) {
    __syncthreads();                          // previous compute done
#pragma unroll
    for (int pln = 0; pln < 9; ++pln) {
      int ii = i + pln / 3 - 1, jj = j + pln % 3 - 1;
      const bool slab_ok = (ii >= 0 && ii < 24 && jj >= 0 && jj < 24); // uniform
      const float* src = xb + (size_t)ci * S4 + (size_t)(ii * 24 + jj) * 576;
#pragma unroll
      for (int q = 0; q < 4; ++q) {
        if (eok[q]) {
          float v = 0.f;
          if (slab_ok && klok[q]) v = src[soff[q]];
          tile[pln * 702 + eidx[q]] = v;
        }
      }
    }
    __syncthreads();
#pragma unroll
    for (int pln = 0; pln < 9; ++pln) {
      const float* base = &tile[pln * 702 + k * 27 + l0];
#pragma unroll
      for (int dk = 0; dk < 3; ++dk) {
        float c0 = base[dk * 27 + 0], c1 = base[dk * 27 + 1],
              c2 = base[dk * 27 + 2], c3 = base[dk * 27 + 3],
              c4 = base[dk * 27 + 4];
#pragma unroll
        for (int co = 0; co < COUT; ++co) {
          const float* wr = w + ((size_t)co * CIN + ci) * 81 + pln * 9 + dk * 3;
          float w0 = wr[0], w1 = wr[1], w2 = wr[2];
          acc[co][0] = fmaf(w0, c0, acc[co][0]);
          acc[co][0] = fmaf(w1, c1, acc[co][0]);
          acc[co][0] = fmaf(w2, c2, acc[co][0]);
          acc[co][1] = fmaf(w0, c1, acc[co][1]);
          acc[co][1] = fmaf(w1, c2, acc[co][1]);
          acc[co][1] = fmaf(w2, c3, acc[co][1]);
          acc[co][2] = fmaf(w0, c2, acc[co][2]);
          acc[co][2] = fmaf(w1, c3, acc[co][2]);
          acc[co][2] = fmaf(w2, c4, acc[co][2]);
        }
      }
    }
  }
#pragma unroll
  for (int co = 0; co < COUT; ++co) {
    float bv = bias[co];
#pragma unroll
    for (int oo = 0; oo < 3; ++oo) {
      float v = fmaxf(acc[co][oo] + bv, 0.f);
      yb[(size_t)co * S4 + (size_t)ij * 576 + k * 24 + l0 + oo] = v;
    }
  }
}

// ---------------------------------------------------------------------------
extern "C" void kernel_launch(void* const* d_in, const int* in_sizes, int n_in,
                              void* d_out, int out_size, void* d_ws, size_t ws_size,
                              hipStream_t stream) {
  const float* fA = (const float*)d_in[0];
  const float* fB = (const float*)d_in[1];
  const float* w1 = (const float*)d_in[2];
  const float* b1 = (const float*)d_in[3];
  const float* w2 = (const float*)d_in[4];
  const float* b2 = (const float*)d_in[5];
  const float* w3 = (const float*)d_in[6];
  const float* b3 = (const float*)d_in[7];
  float* out = (float*)d_out;

  float* ws = (float*)d_ws;
  size_t off = 0;
  auto alloc = [&](size_t n) {
    float* p = ws + off;
    off += (n + 63) & ~(size_t)63;
    return p;
  };
  float* pooled = alloc((size_t)8 * S4);          // 10.6 MB
  float* C3     = alloc((size_t)8 * S4);          // 10.6 MB
  float* part   = alloc((size_t)16 * 16 * P_);    // 2.4 MB
  float* invn   = alloc((size_t)16 * P_);
  float* amax1  = alloc(8 * 576);
  float* bmax1  = alloc(8 * 576);
  float* amax2  = alloc(8 * 576);
  float* bmax2  = alloc(8 * 576);
  float* X = alloc((size_t)20 * S4 * 8);          // C1+C2 overlay T arrays
  float* C1 = X;
  float* C2 = X + (size_t)10 * S4 * 8;
  unsigned short* TAhi = (unsigned short*)X;      // each 8*P_*C_ ushorts
  unsigned short* TAlo = TAhi + (size_t)8 * P_ * C_;
  unsigned short* TBhi = TAlo + (size_t)8 * P_ * C_;
  unsigned short* TBlo = TBhi + (size_t)8 * P_ * C_;
  (void)in_sizes; (void)n_in; (void)out_size; (void)ws_size;

  // 1+2) transpose/split + norms + MFMA correlation — all batches per dispatch
  k_prep<<<dim3(16, 36, 16), 256, 0, stream>>>(fA, fB, TAhi, TAlo, TBhi, TBlo, part);
  k_invnorm<<<dim3(9, 16), 256, 0, stream>>>(part, invn);
  k_corr_mfma<<<dim3(576, 8), 256, 0, stream>>>(TAhi, TAlo, TBhi, TBlo, invn, pooled);

  // 3) mutual matching #1 (in place)
  k_rowmax<<<dim3(8 * 576), 64, 0, stream>>>(pooled, amax1);
  k_colmax<<<dim3(8, 9), 256, 0, stream>>>(pooled, bmax1);
  k_mm_apply<<<dim3(10368), 256, 0, stream>>>(pooled, amax1, bmax1, pooled);

  // 4) neighbourhood consensus: 3x conv4d + relu, all batches per dispatch
  k_conv4d<1, 10><<<dim3(576, 8), 192, 0, stream>>>(
      pooled, (size_t)S4, w1, b1, C1, (size_t)10 * S4);
  k_conv4d<10, 10><<<dim3(576, 8), 192, 0, stream>>>(
      C1, (size_t)10 * S4, w2, b2, C2, (size_t)10 * S4);
  k_conv4d<10, 1><<<dim3(576, 8), 192, 0, stream>>>(
      C2, (size_t)10 * S4, w3, b3, C3, (size_t)S4);

  // 5) mutual matching #2 -> final output
  k_rowmax<<<dim3(8 * 576), 64, 0, stream>>>(C3, amax2);
  k_colmax<<<dim3(8, 9), 256, 0, stream>>>(C3, bmax2);
  k_mm_apply<<<dim3(10368), 256, 0, stream>>>(C3, amax2, bmax2, out);
}

// Round 6
// 1902.910 us; speedup vs baseline: 3.0156x; 1.4317x over previous
//
#include <hip/hip_runtime.h>
#include <hip/hip_bf16.h>
#include <math.h>

#define C_   1024
#define P_   2304      // 48*48
#define S4   331776    // 24^4

typedef __attribute__((ext_vector_type(8))) short short8;
typedef __attribute__((ext_vector_type(4))) float f32x4;

__device__ inline unsigned short f2bf(float v) {
  unsigned u = __builtin_bit_cast(unsigned, v);
  u += 0x7fffu + ((u >> 16) & 1u);          // RNE
  return (unsigned short)(u >> 16);
}
__device__ inline float bf2f(unsigned short h) {
  unsigned u = ((unsigned)h) << 16;
  return __builtin_bit_cast(float, u);
}

// async global->LDS DMA, 16B per lane; LDS dest = wave-uniform base + lane*16
__device__ inline void async16(const void* g, void* l) {
  __builtin_amdgcn_global_load_lds(
      (const __attribute__((address_space(1))) unsigned int*)g,
      (__attribute__((address_space(3))) unsigned int*)l, 16, 0, 0);
}

// ---------------- K1: transpose + bf16 hi/lo split + sumsq partials --------
// grid (16 ctiles, 36 ptiles, 16 fb); fb = f*8 + b.
__global__ __launch_bounds__(256) void k_prep(
    const float* __restrict__ fA, const float* __restrict__ fB,
    unsigned short* __restrict__ TAhi, unsigned short* __restrict__ TAlo,
    unsigned short* __restrict__ TBhi, unsigned short* __restrict__ TBlo,
    float* __restrict__ part) {
  __shared__ float ld[64 * 65];
  __shared__ float pslds[512];
  const int c0 = blockIdx.x * 64, p0 = blockIdx.y * 64;
  const int fb = blockIdx.z, f = fb >> 3, b = fb & 7;
  const float* src = (f ? fB : fA) + (size_t)b * C_ * P_;
  unsigned short* Thi = (f ? TBhi : TAhi) + (size_t)b * P_ * C_;
  unsigned short* Tlo = (f ? TBlo : TAlo) + (size_t)b * P_ * C_;
  const int t = threadIdx.x;
#pragma unroll
  for (int e = 0; e < 4; ++e) {
    int cid = t + e * 256;                  // 0..1023
    int r = cid >> 4, ch = cid & 15;
    float4 v = *(const float4*)&src[(size_t)(c0 + r) * P_ + p0 + ch * 4];
    ld[r * 65 + ch * 4 + 0] = v.x;
    ld[r * 65 + ch * 4 + 1] = v.y;
    ld[r * 65 + ch * 4 + 2] = v.z;
    ld[r * 65 + ch * 4 + 3] = v.w;
  }
  __syncthreads();
#pragma unroll
  for (int e = 0; e < 2; ++e) {
    int ocid = t + e * 256;                 // 0..511
    int pl = ocid >> 3, c8 = ocid & 7;
    unsigned short hi[8], lo[8];
    float sq = 0.f;
#pragma unroll
    for (int s = 0; s < 8; ++s) {
      float v = ld[(c8 * 8 + s) * 65 + pl];
      unsigned short h = f2bf(v);
      float rem = v - bf2f(h);
      hi[s] = h; lo[s] = f2bf(rem);
      sq = fmaf(v, v, sq);
    }
    size_t go = (size_t)(p0 + pl) * C_ + c0 + c8 * 8;
    *(uint4*)&Thi[go] = *(uint4*)hi;
    *(uint4*)&Tlo[go] = *(uint4*)lo;
    pslds[ocid] = sq;
  }
  __syncthreads();
  if (t < 64) {
    float s = 0.f;
#pragma unroll
    for (int c8 = 0; c8 < 8; ++c8) s += pslds[t * 8 + c8];
    part[((size_t)fb * 16 + blockIdx.x) * P_ + p0 + t] = s;
  }
}

// ---------------- K2: finalize inverse norms -------------------------------
__global__ void k_invnorm(const float* __restrict__ part, float* __restrict__ inv) {
  int p = blockIdx.x * 256 + threadIdx.x;
  int fb = blockIdx.y;
  float s = 1e-6f;
  for (int ct = 0; ct < 16; ++ct) s += part[((size_t)fb * 16 + ct) * P_ + p];
  inv[(size_t)fb * P_ + p] = 1.0f / sqrtf(s);
}

// ---------------- K3: bf16x3 MFMA correlation + relu/norm/4D-maxpool -------
// grid (576 tiles, 8 batches). Staging via global_load_lds (direct-to-LDS
// DMA): no register-resident prefetch -> no scratch spills (R4/R5: 2.8 GB/
// dispatch spill writeback). Row = 80B = 5x16B chunks; 5th chunk is a dummy
// load of the row base (L2 hit, pad never read) so the 2-way-free 40-half
// stride is preserved under the lane-contiguous LDS-dest constraint.
__global__ __launch_bounds__(256, 3) void k_corr_mfma(
    const unsigned short* __restrict__ TAhi_, const unsigned short* __restrict__ TAlo_,
    const unsigned short* __restrict__ TBhi_, const unsigned short* __restrict__ TBlo_,
    const float* __restrict__ invn, float* __restrict__ pooled) {
  __shared__ __align__(16) char lds_raw[37248];
  unsigned short* stage = (unsigned short*)lds_raw;   // 4 arrays, stride 3840h
  float* epi = (float*)lds_raw;                       // 96x97 f32 overlay

  const int b = blockIdx.y;
  const size_t tb = (size_t)b * P_ * C_;
  const unsigned short* TAhi = TAhi_ + tb;
  const unsigned short* TAlo = TAlo_ + tb;
  const unsigned short* TBhi = TBhi_ + tb;
  const unsigned short* TBlo = TBlo_ + tb;
  float* out = pooled + (size_t)b * S4;

  // XCD rect 6x12, column-major order inside: resident ~64 blocks cover
  // ~6 A-strips + ~6 B-strips (~4.8 MB) -> near-L2-resident per XCD.
  const int g = blockIdx.x;
  const int xcd = g & 7, idx = g >> 3;                // idx 0..71
  const int ti = (xcd & 3) * 6 + idx % 6;
  const int tj = (xcd >> 2) * 12 + idx / 6;
  const int p0 = ti * 96, q0 = tj * 96;
  const int t = threadIdx.x;
  const int lane = t & 63, w = t >> 6;
  const int wr = w >> 1, wc = w & 1;
  const int m15 = lane & 15, q4 = lane >> 4;
  const int koff = q4 * 8;

  f32x4 acc[3][3];
#pragma unroll
  for (int a = 0; a < 3; ++a)
#pragma unroll
    for (int c = 0; c < 3; ++c) acc[a][c] = (f32x4){0.f, 0.f, 0.f, 0.f};

  // chunk map: chunk = (w*8+e)*64 + lane in [0,2048); (arr,row,kc) with
  // kc==4 = pad chunk (dummy), chunk>=1920 = tail (dummy).
  const unsigned short* gld[8];
  int ldsb[8];
#pragma unroll
  for (int e = 0; e < 8; ++e) {
    int chunk = (w * 8 + e) * 64 + lane;
    int arr = chunk / 480;
    int rem = chunk - arr * 480;
    int row = rem / 5, kc = rem - row * 5;
    bool dum = (arr >= 4) || (kc == 4);
    if (arr >= 4) { arr = 0; row = 0; }
    const unsigned short* base = (arr == 0) ? TAhi : (arr == 1) ? TAlo
                               : (arr == 2) ? TBhi : TBlo;
    int pb = (arr < 2) ? p0 : q0;
    gld[e] = base + (size_t)(pb + row) * C_ + (dum ? 0 : kc * 8);
    ldsb[e] = (w * 8 + e) * 1024;           // wave-uniform byte offset
  }

  for (int kt = 0; kt < C_; kt += 32) {
    __syncthreads();                        // frag reads of prev iter done
#pragma unroll
    for (int e = 0; e < 8; ++e)
      async16(gld[e] + kt, lds_raw + ldsb[e]);
    asm volatile("s_waitcnt vmcnt(0)" ::: "memory");
    __syncthreads();                        // stage ready

    const unsigned short* Ah = stage;
    const unsigned short* Al = stage + 3840;
    const unsigned short* Bh = stage + 7680;
    const unsigned short* Bl = stage + 11520;
    short8 ah[3], al[3], bh[3], bl[3];
#pragma unroll
    for (int a = 0; a < 3; ++a) {
      int row = wr * 48 + a * 16 + m15;
      ah[a] = *(const short8*)&Ah[row * 40 + koff];
      al[a] = *(const short8*)&Al[row * 40 + koff];
    }
#pragma unroll
    for (int c = 0; c < 3; ++c) {
      int row = wc * 48 + c * 16 + m15;
      bh[c] = *(const short8*)&Bh[row * 40 + koff];
      bl[c] = *(const short8*)&Bl[row * 40 + koff];
    }
#pragma unroll
    for (int a = 0; a < 3; ++a)
#pragma unroll
      for (int c = 0; c < 3; ++c)
        acc[a][c] = __builtin_amdgcn_mfma_f32_16x16x32_bf16(ah[a], bh[c], acc[a][c], 0, 0, 0);
#pragma unroll
    for (int a = 0; a < 3; ++a)
#pragma unroll
      for (int c = 0; c < 3; ++c)
        acc[a][c] = __builtin_amdgcn_mfma_f32_16x16x32_bf16(ah[a], bl[c], acc[a][c], 0, 0, 0);
#pragma unroll
    for (int a = 0; a < 3; ++a)
#pragma unroll
      for (int c = 0; c < 3; ++c)
        acc[a][c] = __builtin_amdgcn_mfma_f32_16x16x32_bf16(al[a], bh[c], acc[a][c], 0, 0, 0);
  }
  __syncthreads();   // all frag reads done before overwriting stage with epi

  const float* invA = invn + (size_t)b * P_;
  const float* invB = invn + (size_t)(8 + b) * P_;
  float ib[3];
#pragma unroll
  for (int c = 0; c < 3; ++c) ib[c] = invB[q0 + wc * 48 + c * 16 + m15];
#pragma unroll
  for (int a = 0; a < 3; ++a) {
#pragma unroll
    for (int reg = 0; reg < 4; ++reg) {
      int pl = wr * 48 + a * 16 + q4 * 4 + reg;
      float ia = invA[p0 + pl];
#pragma unroll
      for (int c = 0; c < 3; ++c) {
        int ql = wc * 48 + c * 16 + m15;
        epi[pl * 97 + ql] = acc[a][c][reg] * ia * ib[c];
      }
    }
  }
  __syncthreads();

  for (int idx2 = t; idx2 < 576; idx2 += 256) {
    int j = idx2 / 24, l = idx2 % 24;
    float m = -1e30f;
#pragma unroll
    for (int dh = 0; dh < 2; ++dh)
#pragma unroll
      for (int dw = 0; dw < 2; ++dw) {
        int row = dh * 48 + 2 * j + dw;
#pragma unroll
        for (int d2 = 0; d2 < 2; ++d2)
#pragma unroll
          for (int dw2 = 0; dw2 < 2; ++dw2)
            m = fmaxf(m, epi[row * 97 + d2 * 48 + 2 * l + dw2]);
      }
    float r = fmaxf(m, 0.f);
    float v = r / sqrtf(r * r + 1e-6f);
    out[(size_t)(ti * 24 + j) * 576 + tj * 24 + l] = v;
  }
}

// ---------------- K4a: row max (over kl, per ij) ---------------------------
__global__ void k_rowmax(const float* __restrict__ x, float* __restrict__ amax) {
  int row = blockIdx.x;                       // b*576 + ij
  const float* r = x + (size_t)row * 576;
  float m = -1e30f;
  for (int e = threadIdx.x; e < 576; e += 64) m = fmaxf(m, r[e]);
  for (int off = 32; off > 0; off >>= 1) m = fmaxf(m, __shfl_down(m, off, 64));
  if (threadIdx.x == 0) amax[row] = m;
}

// ---------------- K4b: col max (over ij, per kl) ---------------------------
__global__ void k_colmax(const float* __restrict__ x, float* __restrict__ bmax) {
  __shared__ float pl[4][64];
  int b = blockIdx.x, klc = blockIdx.y * 64;
  int t = threadIdx.x;
  int kl = klc + (t & 63), seg = t >> 6;
  const float* xb = x + (size_t)b * S4;
  float m = -1e30f;
  for (int ij = seg * 144; ij < (seg + 1) * 144; ++ij)
    m = fmaxf(m, xb[(size_t)ij * 576 + kl]);
  pl[seg][t & 63] = m;
  __syncthreads();
  if (t < 64) {
    float r = fmaxf(fmaxf(pl[0][t], pl[1][t]), fmaxf(pl[2][t], pl[3][t]));
    bmax[b * 576 + klc + t] = r;
  }
}

// ---------------- K5: mutual matching elementwise --------------------------
__global__ void k_mm_apply(const float* __restrict__ x,
                           const float* __restrict__ amax,
                           const float* __restrict__ bmax,
                           float* __restrict__ y) {
  int i = blockIdx.x * 256 + threadIdx.x;     // < 8*S4
  int b = i / S4, r = i % S4;
  int ij = r / 576, kl = r % 576;
  float c = x[i];
  y[i] = c * (c / (amax[b * 576 + ij] + 1e-5f)) * (c / (bmax[b * 576 + kl] + 1e-5f));
}

// ---------------- K6: 4D conv — 192 thr, 3 outputs/thread ------------------
template <int CIN, int COUT>
__global__ __launch_bounds__(192, 4) void k_conv4d(
    const float* __restrict__ x, size_t xbs,
    const float* __restrict__ w, const float* __restrict__ bias,
    float* __restrict__ y, size_t ybs) {
  __shared__ float tile[9 * 702];             // 702 = 26 rows * 27
  const float* xb = x + xbs * blockIdx.y;
  float* yb = y + ybs * blockIdx.y;
  const int ij = blockIdx.x;
  const int i = ij / 24, j = ij % 24;
  const int t = threadIdx.x;                  // 0..191
  const int k = t >> 3;                       // 0..23
  const int l0 = (t & 7) * 3;                 // 0,3,..,21

  int soff[4]; bool eok[4], klok[4]; int eidx[4];
#pragma unroll
  for (int q = 0; q < 4; ++q) {
    int e = t + q * 192;
    eidx[q] = e; eok[q] = (e < 702);
    int row = e / 27, col = e % 27;           // halo coords
    klok[q] = (row >= 1 && row < 25 && col >= 1 && col < 25);
    soff[q] = (row - 1) * 24 + (col - 1);
  }

  float acc[COUT][3];
#pragma unroll
  for (int co = 0; co < COUT; ++co)
#pragma unroll
    for (int oo = 0; oo < 3; ++oo) acc[co][oo] = 0.f;

  for (int ci = 0; ci < CIN; ++ci) {
    __syncthreads();                          // previous compute done
#pragma unroll
    for (int pln = 0; pln < 9; ++pln) {
      int ii = i + pln / 3 - 1, jj = j + pln % 3 - 1;
      const bool slab_ok = (ii >= 0 && ii < 24 && jj >= 0 && jj < 24); // uniform
      const float* src = xb + (size_t)ci * S4 + (size_t)(ii * 24 + jj) * 576;
#pragma unroll
      for (int q = 0; q < 4; ++q) {
        if (eok[q]) {
          float v = 0.f;
          if (slab_ok && klok[q]) v = src[soff[q]];
          tile[pln * 702 + eidx[q]] = v;
        }
      }
    }
    __syncthreads();
#pragma unroll
    for (int pln = 0; pln < 9; ++pln) {
      const float* base = &tile[pln * 702 + k * 27 + l0];
#pragma unroll
      for (int dk = 0; dk < 3; ++dk) {
        float c0 = base[dk * 27 + 0], c1 = base[dk * 27 + 1],
              c2 = base[dk * 27 + 2], c3 = base[dk * 27 + 3],
              c4 = base[dk * 27 + 4];
#pragma unroll
        for (int co = 0; co < COUT; ++co) {
          const float* wr = w + ((size_t)co * CIN + ci) * 81 + pln * 9 + dk * 3;
          float w0 = wr[0], w1 = wr[1], w2 = wr[2];
          acc[co][0] = fmaf(w0, c0, acc[co][0]);
          acc[co][0] = fmaf(w1, c1, acc[co][0]);
          acc[co][0] = fmaf(w2, c2, acc[co][0]);
          acc[co][1] = fmaf(w0, c1, acc[co][1]);
          acc[co][1] = fmaf(w1, c2, acc[co][1]);
          acc[co][1] = fmaf(w2, c3, acc[co][1]);
          acc[co][2] = fmaf(w0, c2, acc[co][2]);
          acc[co][2] = fmaf(w1, c3, acc[co][2]);
          acc[co][2] = fmaf(w2, c4, acc[co][2]);
        }
      }
    }
  }
#pragma unroll
  for (int co = 0; co < COUT; ++co) {
    float bv = bias[co];
#pragma unroll
    for (int oo = 0; oo < 3; ++oo) {
      float v = fmaxf(acc[co][oo] + bv, 0.f);
      yb[(size_t)co * S4 + (size_t)ij * 576 + k * 24 + l0 + oo] = v;
    }
  }
}

// ---------------------------------------------------------------------------
extern "C" void kernel_launch(void* const* d_in, const int* in_sizes, int n_in,
                              void* d_out, int out_size, void* d_ws, size_t ws_size,
                              hipStream_t stream) {
  const float* fA = (const float*)d_in[0];
  const float* fB = (const float*)d_in[1];
  const float* w1 = (const float*)d_in[2];
  const float* b1 = (const float*)d_in[3];
  const float* w2 = (const float*)d_in[4];
  const float* b2 = (const float*)d_in[5];
  const float* w3 = (const float*)d_in[6];
  const float* b3 = (const float*)d_in[7];
  float* out = (float*)d_out;

  float* ws = (float*)d_ws;
  size_t off = 0;
  auto alloc = [&](size_t n) {
    float* p = ws + off;
    off += (n + 63) & ~(size_t)63;
    return p;
  };
  float* pooled = alloc((size_t)8 * S4);          // 10.6 MB
  float* C3     = alloc((size_t)8 * S4);          // 10.6 MB
  float* part   = alloc((size_t)16 * 16 * P_);    // 2.4 MB
  float* invn   = alloc((size_t)16 * P_);
  float* amax1  = alloc(8 * 576);
  float* bmax1  = alloc(8 * 576);
  float* amax2  = alloc(8 * 576);
  float* bmax2  = alloc(8 * 576);
  float* X = alloc((size_t)20 * S4 * 8);          // C1+C2 overlay T arrays
  float* C1 = X;
  float* C2 = X + (size_t)10 * S4 * 8;
  unsigned short* TAhi = (unsigned short*)X;      // each 8*P_*C_ ushorts
  unsigned short* TAlo = TAhi + (size_t)8 * P_ * C_;
  unsigned short* TBhi = TAlo + (size_t)8 * P_ * C_;
  unsigned short* TBlo = TBhi + (size_t)8 * P_ * C_;
  (void)in_sizes; (void)n_in; (void)out_size; (void)ws_size;

  // 1+2) transpose/split + norms + MFMA correlation — all batches per dispatch
  k_prep<<<dim3(16, 36, 16), 256, 0, stream>>>(fA, fB, TAhi, TAlo, TBhi, TBlo, part);
  k_invnorm<<<dim3(9, 16), 256, 0, stream>>>(part, invn);
  k_corr_mfma<<<dim3(576, 8), 256, 0, stream>>>(TAhi, TAlo, TBhi, TBlo, invn, pooled);

  // 3) mutual matching #1 (in place)
  k_rowmax<<<dim3(8 * 576), 64, 0, stream>>>(pooled, amax1);
  k_colmax<<<dim3(8, 9), 256, 0, stream>>>(pooled, bmax1);
  k_mm_apply<<<dim3(10368), 256, 0, stream>>>(pooled, amax1, bmax1, pooled);

  // 4) neighbourhood consensus: 3x conv4d + relu, all batches per dispatch
  k_conv4d<1, 10><<<dim3(576, 8), 192, 0, stream>>>(
      pooled, (size_t)S4, w1, b1, C1, (size_t)10 * S4);
  k_conv4d<10, 10><<<dim3(576, 8), 192, 0, stream>>>(
      C1, (size_t)10 * S4, w2, b2, C2, (size_t)10 * S4);
  k_conv4d<10, 1><<<dim3(576, 8), 192, 0, stream>>>(
      C2, (size_t)10 * S4, w3, b3, C3, (size_t)S4);

  // 5) mutual matching #2 -> final output
  k_rowmax<<<dim3(8 * 576), 64, 0, stream>>>(C3, amax2);
  k_colmax<<<dim3(8, 9), 256, 0, stream>>>(C3, bmax2);
  k_mm_apply<<<dim3(10368), 256, 0, stream>>>(C3, amax2, bmax2, out);
}